// Round 2
// baseline (1498.159 us; speedup 1.0000x reference)
//
#include <hip/hip_runtime.h>

#define SEQ 128
#define HID 32
#define NPB 16        // nodes per block
#define TPB 128       // threads per block = NPB * 8
#define WSTRIDE 17    // float4 per weight row (16 data + 1 pad -> conflict-free w/ interleaved units)
#define ESTRIDE 9     // float4 per exchange row (8 data + 1 pad)

// ---------------- GCN prep ----------------

__global__ void count_kernel(const int* __restrict__ idx, int E, int* __restrict__ cnt) {
    int e = blockIdx.x * blockDim.x + threadIdx.x;
    if (e < E) atomicAdd(&cnt[idx[E + e]], 1);
}

__global__ void dinv_kernel(float* __restrict__ buf, int n) {
    int i = blockIdx.x * blockDim.x + threadIdx.x;
    if (i < n) buf[i] = rsqrtf((float)__float_as_int(buf[i]) + 1.0f);
}

// Scatter pre-transform features into TIME-MAJOR accumulator:
// u_t[t*N + node] += x[src] * (dinv[src]*dinv[dst]).  (weight commuted by linearity)
__global__ void scatter_kernel(const int* __restrict__ idx, int E, int N,
                               const float2* __restrict__ x2,
                               const float* __restrict__ dinv,
                               float* __restrict__ u_t) {
    int e = blockIdx.x * blockDim.x + threadIdx.x;
    if (e < E) {
        int s = idx[e], d = idx[E + e];
        float norm = dinv[s] * dinv[d];
        float2 xs = x2[s];
        int t = d & (SEQ - 1), n = d >> 7;
        float* p = u_t + 2 * ((size_t)t * N + n);
        atomicAdd(p + 0, xs.x * norm);
        atomicAdd(p + 1, xs.y * norm);
    }
}

// ---------------- fused GCN-linear + LSTM + FC ----------------
// 8 lanes per node; lane j (=tid&7) owns hidden units {j, j+8, j+16, j+24}.
// Gate rows owned: r = g*32 + 8i + j  (g = 0..3 -> i,f,g,o ; i = 0..3).
// Weights in LDS, column-interleaved so operand float4 chunk k = units
// {k, k+8, k+16, k+24} pairs with weight chunk k. Row stride 17 float4 makes
// the 8 lane-positions hit 8 distinct bank-groups (68*j mod 32 = 4j) -> no conflicts.
// xg/h exchanged through padded LDS rows; groups are intra-wave -> NO barriers in loop.

__device__ __forceinline__ float sigm_f(float x) {
    return __fdividef(1.0f, 1.0f + __expf(-x));
}
__device__ __forceinline__ float tanh_f(float x) {
    // 1 - 2/(e^{2x}+1); saturates correctly for |x| large
    return 1.0f - __fdividef(2.0f, __expf(2.0f * x) + 1.0f);
}

__global__ __launch_bounds__(TPB, 2) void lstm_kernel(
    const float2* __restrict__ x2, const float* __restrict__ dinv,
    const float2* __restrict__ u_t, int N,
    const float* __restrict__ gcn_W, const float* __restrict__ gcn_b,
    const float* __restrict__ w_ih, const float* __restrict__ w_hh,
    const float* __restrict__ b_ih, const float* __restrict__ b_hh,
    const float* __restrict__ fc_W, const float* __restrict__ fc_b,
    float* __restrict__ out) {
    __shared__ float4 wlds[4 * HID * WSTRIDE];  // 34816 B
    __shared__ float4 exx[NPB * ESTRIDE];       // xg exchange, 2304 B
    __shared__ float4 exh[NPB * ESTRIDE];       // h exchange, 2304 B

    const int tid = threadIdx.x;
    const int j = tid & 7;
    const int nb = tid >> 3;
    int node = blockIdx.x * NPB + nb;
    const bool valid = node < N;
    if (node >= N) node = N - 1;  // clamp loads; store guarded

    // ---- stage weights (column-interleaved) ----
    for (int i = tid; i < 4 * HID * 16; i += TPB) {
        int r = i >> 4, k = i & 15;
        const float* src = (k < 8) ? (w_ih + r * HID + k) : (w_hh + r * HID + (k - 8));
        wlds[r * WSTRIDE + k] = make_float4(src[0], src[8], src[16], src[24]);
    }

    // ---- per-lane constants for owned units/rows ----
    float bias[4][4], Wg0[4], Wg1[4], gbc[4], fcw[4];
    #pragma unroll
    for (int i = 0; i < 4; ++i) {
        const int u = 8 * i + j;
        #pragma unroll
        for (int g = 0; g < 4; ++g) {
            const int r = g * HID + u;
            bias[i][g] = b_ih[r] + b_hh[r];
        }
        Wg0[i] = gcn_W[u];
        Wg1[i] = gcn_W[HID + u];
        gbc[i] = gcn_b[u];
        fcw[i] = fc_W[u];
    }
    const float fcb = fc_b[0];

    exh[nb * ESTRIDE + j] = make_float4(0.f, 0.f, 0.f, 0.f);  // h0 = 0
    float c[4] = {0.f, 0.f, 0.f, 0.f};
    float ho[4] = {0.f, 0.f, 0.f, 0.f};

    __syncthreads();  // weights staged, h init visible (once, outside loop)

    const float2* uptr = u_t + node;
    const float2* xptr = x2 + (size_t)node * SEQ;
    const float*  dptr = dinv + (size_t)node * SEQ;

    for (int t = 0; t < SEQ; ++t) {
        // u with self-loop folded in: u += x * dinv^2
        float2 uu = *uptr; uptr += N;
        float2 xx = xptr[t];
        float dv = dptr[t];
        float s2 = dv * dv;
        float ux = fmaf(xx.x, s2, uu.x);
        float uy = fmaf(xx.y, s2, uu.y);

        // xg for owned units (GCN linear + bias + relu)
        float4 xo;
        xo.x = fmaxf(fmaf(ux, Wg0[0], fmaf(uy, Wg1[0], gbc[0])), 0.f);
        xo.y = fmaxf(fmaf(ux, Wg0[1], fmaf(uy, Wg1[1], gbc[1])), 0.f);
        xo.z = fmaxf(fmaf(ux, Wg0[2], fmaf(uy, Wg1[2], gbc[2])), 0.f);
        xo.w = fmaxf(fmaf(ux, Wg0[3], fmaf(uy, Wg1[3], gbc[3])), 0.f);

        __builtin_amdgcn_wave_barrier();
        exx[nb * ESTRIDE + j] = xo;
        __builtin_amdgcn_wave_barrier();

        // gather full xg / h(t-1) for this node (broadcast reads, conflict-free)
        float4 xgf[8], hf[8];
        #pragma unroll
        for (int m = 0; m < 8; ++m) {
            xgf[m] = exx[nb * ESTRIDE + m];
            hf[m]  = exh[nb * ESTRIDE + m];
        }

        // ---- 16 gate rows: 1024 FMAs ----
        #pragma unroll
        for (int i = 0; i < 4; ++i) {
            const int u = 8 * i + j;
            float a0 = bias[i][0], a1 = bias[i][1], a2 = bias[i][2], a3 = bias[i][3];
            #pragma unroll
            for (int k = 0; k < 8; ++k) {
                const float4 xv = xgf[k];
                const float4 hv = hf[k];
                const float4 w0 = wlds[(0 * HID + u) * WSTRIDE + k];
                const float4 w1 = wlds[(1 * HID + u) * WSTRIDE + k];
                const float4 w2 = wlds[(2 * HID + u) * WSTRIDE + k];
                const float4 w3 = wlds[(3 * HID + u) * WSTRIDE + k];
                const float4 v0 = wlds[(0 * HID + u) * WSTRIDE + 8 + k];
                const float4 v1 = wlds[(1 * HID + u) * WSTRIDE + 8 + k];
                const float4 v2 = wlds[(2 * HID + u) * WSTRIDE + 8 + k];
                const float4 v3 = wlds[(3 * HID + u) * WSTRIDE + 8 + k];
                a0 = fmaf(xv.x, w0.x, a0); a0 = fmaf(xv.y, w0.y, a0);
                a0 = fmaf(xv.z, w0.z, a0); a0 = fmaf(xv.w, w0.w, a0);
                a1 = fmaf(xv.x, w1.x, a1); a1 = fmaf(xv.y, w1.y, a1);
                a1 = fmaf(xv.z, w1.z, a1); a1 = fmaf(xv.w, w1.w, a1);
                a2 = fmaf(xv.x, w2.x, a2); a2 = fmaf(xv.y, w2.y, a2);
                a2 = fmaf(xv.z, w2.z, a2); a2 = fmaf(xv.w, w2.w, a2);
                a3 = fmaf(xv.x, w3.x, a3); a3 = fmaf(xv.y, w3.y, a3);
                a3 = fmaf(xv.z, w3.z, a3); a3 = fmaf(xv.w, w3.w, a3);
                a0 = fmaf(hv.x, v0.x, a0); a0 = fmaf(hv.y, v0.y, a0);
                a0 = fmaf(hv.z, v0.z, a0); a0 = fmaf(hv.w, v0.w, a0);
                a1 = fmaf(hv.x, v1.x, a1); a1 = fmaf(hv.y, v1.y, a1);
                a1 = fmaf(hv.z, v1.z, a1); a1 = fmaf(hv.w, v1.w, a1);
                a2 = fmaf(hv.x, v2.x, a2); a2 = fmaf(hv.y, v2.y, a2);
                a2 = fmaf(hv.z, v2.z, a2); a2 = fmaf(hv.w, v2.w, a2);
                a3 = fmaf(hv.x, v3.x, a3); a3 = fmaf(hv.y, v3.y, a3);
                a3 = fmaf(hv.z, v3.z, a3); a3 = fmaf(hv.w, v3.w, a3);
            }
            const float ig = sigm_f(a0);
            const float fg = sigm_f(a1);
            const float gg = tanh_f(a2);
            const float og = sigm_f(a3);
            c[i] = fmaf(fg, c[i], ig * gg);
            ho[i] = og * tanh_f(c[i]);
        }

        __builtin_amdgcn_wave_barrier();
        exh[nb * ESTRIDE + j] = make_float4(ho[0], ho[1], ho[2], ho[3]);
        __builtin_amdgcn_wave_barrier();
    }

    // ---- FC epilogue: reduce over the 8-lane group ----
    float partial = fmaf(ho[0], fcw[0],
                    fmaf(ho[1], fcw[1],
                    fmaf(ho[2], fcw[2], ho[3] * fcw[3])));
    partial += __shfl_xor(partial, 1);
    partial += __shfl_xor(partial, 2);
    partial += __shfl_xor(partial, 4);
    if (j == 0 && valid) out[node] = partial + fcb;
}

extern "C" void kernel_launch(void* const* d_in, const int* in_sizes, int n_in,
                              void* d_out, int out_size, void* d_ws, size_t ws_size,
                              hipStream_t stream) {
    const float* x     = (const float*)d_in[0];
    const int*   idx   = (const int*)d_in[1];
    const float* gcn_W = (const float*)d_in[2];
    const float* gcn_b = (const float*)d_in[3];
    const float* w_ih  = (const float*)d_in[4];
    const float* w_hh  = (const float*)d_in[5];
    const float* b_ih  = (const float*)d_in[6];
    const float* b_hh  = (const float*)d_in[7];
    const float* fc_W  = (const float*)d_in[8];
    const float* fc_b  = (const float*)d_in[9];

    const int num_nodes = in_sizes[0] / (SEQ * 2);
    const int ntot = num_nodes * SEQ;
    const int E = in_sizes[1] / 2;

    // ws layout: [dinv: ntot floats][u_t: ntot float2 (time-major)]
    float* dinv = (float*)d_ws;
    float* u_t  = dinv + ntot;

    hipMemsetAsync(d_ws, 0, (size_t)ntot * sizeof(float) * 3, stream);

    count_kernel<<<(E + 255) / 256, 256, 0, stream>>>(idx, E, (int*)dinv);
    dinv_kernel<<<(ntot + 255) / 256, 256, 0, stream>>>(dinv, ntot);
    scatter_kernel<<<(E + 255) / 256, 256, 0, stream>>>(
        idx, E, num_nodes, (const float2*)x, dinv, u_t);
    lstm_kernel<<<(num_nodes + NPB - 1) / NPB, TPB, 0, stream>>>(
        (const float2*)x, dinv, (const float2*)u_t, num_nodes,
        gcn_W, gcn_b, w_ih, w_hh, b_ih, b_hh, fc_W, fc_b,
        (float*)d_out);
}

// Round 3
// 1103.621 us; speedup vs baseline: 1.3575x; 1.3575x over previous
//
#include <hip/hip_runtime.h>

#define SEQ_LEN 128
#define IN_FEATS 2
#define HID 32

// ---------------- GCN prep ----------------

__global__ void count_kernel(const int* __restrict__ idx, int E, int* __restrict__ cnt) {
    int e = blockIdx.x * blockDim.x + threadIdx.x;
    if (e < E) atomicAdd(&cnt[idx[E + e]], 1);
}

__global__ void dinv_kernel(float* __restrict__ buf, int n) {
    int i = blockIdx.x * blockDim.x + threadIdx.x;
    if (i < n) buf[i] = rsqrtf((float)__float_as_int(buf[i]) + 1.0f);
}

// agg2[dst] += x[src] * (dinv[src]*dinv[dst]); weight commuted past the sum
// by linearity -> scatter 2-dim raw features (16x fewer atomic bytes).
__global__ void scatter_kernel(const int* __restrict__ idx, int E,
                               const float2* __restrict__ x2,
                               const float* __restrict__ dinv,
                               float* __restrict__ agg2) {
    int e = blockIdx.x * blockDim.x + threadIdx.x;
    if (e < E) {
        int s = idx[e];
        int d = idx[E + e];
        float norm = dinv[s] * dinv[d];
        float2 xs = x2[s];
        atomicAdd(&agg2[2 * d + 0], xs.x * norm);
        atomicAdd(&agg2[2 * d + 1], xs.y * norm);
    }
}

// ---------------- fused GCN-epilogue + LSTM + FC ----------------
// One wave per node. Lane l owns gate rows l and l+64 (rows 0..31=i, 32..63=f,
// 64..95=g, 96..127=o):  lane<32 -> (i[l], g[l]);  lane>=32 -> (f[l-32], o[l-32]).
// Weights for the two owned rows are REGISTER-resident: 32 float4 = 128 VGPR.
// __launch_bounds__(64,2) caps VGPR at 256 so the compiler can keep them
// (round 1 defaulted to 84 VGPRs and re-fetched weights every step).
// xg_t / h_t broadcast via LDS same-address reads; exchange is intra-wave so
// wave_barrier (free) replaces __syncthreads.
__global__ __launch_bounds__(64, 2) void lstm_kernel(
    const float2* __restrict__ x2, const float* __restrict__ dinv,
    const float2* __restrict__ agg2,
    const float* __restrict__ gcn_W, const float* __restrict__ gcn_b,
    const float* __restrict__ w_ih, const float* __restrict__ w_hh,
    const float* __restrict__ b_ih, const float* __restrict__ b_hh,
    const float* __restrict__ fc_W, const float* __restrict__ fc_b,
    float* __restrict__ out) {
    __shared__ float2 uarr[SEQ_LEN];   // pre-GCN-linear 2-vec per timestep
    __shared__ float4 xgbuf[HID / 4];  // xg_t (32 floats)
    __shared__ float4 hbuf[HID / 4];   // h_t  (32 floats)

    const int node = blockIdx.x;
    const int lane = threadIdx.x;
    const int k = lane & 31;
    const bool lo = lane < 32;
    const int rbase = node * SEQ_LEN;

    // Phase A: u[t] = agg2[r] + x[r] * dinv[r]^2   (self-loop term)
    #pragma unroll
    for (int p = 0; p < 2; ++p) {
        int t = lane + p * 64;
        int r = rbase + t;
        float dv = dinv[r];
        float idv = dv * dv;
        float2 a = agg2[r];
        float2 xx = x2[r];
        uarr[t] = make_float2(fmaf(xx.x, idv, a.x), fmaf(xx.y, idv, a.y));
    }

    // Per-lane weights: rows (lane) and (lane+64) of w_ih / w_hh -> registers.
    float4 wia[8], wib[8], wha[8], whb[8];
    const float4* wi4 = reinterpret_cast<const float4*>(w_ih);
    const float4* wh4 = reinterpret_cast<const float4*>(w_hh);
    #pragma unroll
    for (int kk = 0; kk < 8; ++kk) {
        wia[kk] = wi4[lane * 8 + kk];
        wib[kk] = wi4[(lane + 64) * 8 + kk];
        wha[kk] = wh4[lane * 8 + kk];
        whb[kk] = wh4[(lane + 64) * 8 + kk];
    }
    const float bsa = b_ih[lane] + b_hh[lane];
    const float bsb = b_ih[lane + 64] + b_hh[lane + 64];

    // GCN linear constants (column k of W, bias k) — used by lo half.
    const float W0 = gcn_W[k];
    const float W1 = gcn_W[HID + k];
    const float gb = gcn_b[k];

    // act_b: lo lanes need tanh(g)=2*sigm(2g)-1; hi lanes need sigm(o).
    const float nb_scale = lo ? -2.0f : -1.0f;
    const float mb = lo ? 2.0f : 1.0f;
    const float ab = lo ? -1.0f : 0.0f;

    if (lo) ((float*)hbuf)[k] = 0.0f;
    float c = 0.0f;
    float hn = 0.0f;
    __builtin_amdgcn_wave_barrier();

    for (int t = 0; t < SEQ_LEN; ++t) {
        if (lo) {
            float2 u = uarr[t];
            float xg = fmaf(u.x, W0, fmaf(u.y, W1, gb));
            ((float*)xgbuf)[k] = fmaxf(xg, 0.0f);
        }
        __builtin_amdgcn_wave_barrier();

        float axa = 0.0f, aha = 0.0f, axb = 0.0f, ahb = 0.0f;  // 4 indep chains
        #pragma unroll
        for (int kk = 0; kk < 8; ++kk) {
            float4 xv = xgbuf[kk];
            float4 hv = hbuf[kk];
            axa = fmaf(xv.x, wia[kk].x, axa);
            axa = fmaf(xv.y, wia[kk].y, axa);
            axa = fmaf(xv.z, wia[kk].z, axa);
            axa = fmaf(xv.w, wia[kk].w, axa);
            aha = fmaf(hv.x, wha[kk].x, aha);
            aha = fmaf(hv.y, wha[kk].y, aha);
            aha = fmaf(hv.z, wha[kk].z, aha);
            aha = fmaf(hv.w, wha[kk].w, aha);
            axb = fmaf(xv.x, wib[kk].x, axb);
            axb = fmaf(xv.y, wib[kk].y, axb);
            axb = fmaf(xv.z, wib[kk].z, axb);
            axb = fmaf(xv.w, wib[kk].w, axb);
            ahb = fmaf(hv.x, whb[kk].x, ahb);
            ahb = fmaf(hv.y, whb[kk].y, ahb);
            ahb = fmaf(hv.z, whb[kk].z, ahb);
            ahb = fmaf(hv.w, whb[kk].w, ahb);
        }
        float ga = bsa + axa + aha;   // row lane   : i (lo) / f (hi)
        float gbv = bsb + axb + ahb;  // row lane+64: g (lo) / o (hi)

        float ea = __expf(-ga);
        float act_a = __fdividef(1.0f, 1.0f + ea);                // sigmoid
        float eb = __expf(gbv * nb_scale);
        float act_b = fmaf(__fdividef(1.0f, 1.0f + eb), mb, ab);  // tanh | sigm

        float oth_a = __shfl_xor(act_a, 32);
        float oth_b = __shfl_xor(act_b, 32);
        float ii = lo ? act_a : oth_a;
        float gg = lo ? act_b : oth_b;
        float ff = lo ? oth_a : act_a;
        float oo = lo ? oth_b : act_b;

        c = fmaf(ff, c, ii * gg);
        float ec = __expf(-2.0f * c);
        float th = fmaf(__fdividef(1.0f, 1.0f + ec), 2.0f, -1.0f);  // tanh(c)
        hn = oo * th;

        __builtin_amdgcn_wave_barrier();
        if (lo) ((float*)hbuf)[k] = hn;
        __builtin_amdgcn_wave_barrier();
    }

    // FC epilogue: both halves hold identical hn per unit k; reduce 32 lanes.
    float val = hn * fc_W[k];
    #pragma unroll
    for (int off = 16; off; off >>= 1) val += __shfl_xor(val, off);
    if (lane == 0) out[node] = val + fc_b[0];
}

extern "C" void kernel_launch(void* const* d_in, const int* in_sizes, int n_in,
                              void* d_out, int out_size, void* d_ws, size_t ws_size,
                              hipStream_t stream) {
    const float* x     = (const float*)d_in[0];
    const int*   idx   = (const int*)d_in[1];
    const float* gcn_W = (const float*)d_in[2];
    const float* gcn_b = (const float*)d_in[3];
    const float* w_ih  = (const float*)d_in[4];
    const float* w_hh  = (const float*)d_in[5];
    const float* b_ih  = (const float*)d_in[6];
    const float* b_hh  = (const float*)d_in[7];
    const float* fc_W  = (const float*)d_in[8];
    const float* fc_b  = (const float*)d_in[9];

    const int num_nodes = in_sizes[0] / (SEQ_LEN * IN_FEATS);
    const int ntot = num_nodes * SEQ_LEN;
    const int E = in_sizes[1] / 2;

    // ws layout: [dinv: ntot floats][agg2: ntot float2]
    float* dinv = (float*)d_ws;
    float* agg2 = dinv + ntot;

    hipMemsetAsync(d_ws, 0, (size_t)ntot * sizeof(float) * 3, stream);

    count_kernel<<<(E + 255) / 256, 256, 0, stream>>>(idx, E, (int*)dinv);
    dinv_kernel<<<(ntot + 255) / 256, 256, 0, stream>>>(dinv, ntot);
    scatter_kernel<<<(E + 255) / 256, 256, 0, stream>>>(
        idx, E, (const float2*)x, dinv, agg2);
    lstm_kernel<<<num_nodes, 64, 0, stream>>>(
        (const float2*)x, dinv, (const float2*)agg2,
        gcn_W, gcn_b, w_ih, w_hh, b_ih, b_hh, fc_W, fc_b,
        (float*)d_out);
}

// Round 4
// 1086.509 us; speedup vs baseline: 1.3789x; 1.0157x over previous
//
#include <hip/hip_runtime.h>

#define SEQ_LEN 128
#define IN_FEATS 2
#define HID 32

// ---------------- GCN prep ----------------

__global__ void count_kernel(const int* __restrict__ idx, int E, int* __restrict__ cnt) {
    int e = blockIdx.x * blockDim.x + threadIdx.x;
    if (e < E) atomicAdd(&cnt[idx[E + e]], 1);
}

__global__ void dinv_kernel(float* __restrict__ buf, int n) {
    int i = blockIdx.x * blockDim.x + threadIdx.x;
    if (i < n) buf[i] = rsqrtf((float)__float_as_int(buf[i]) + 1.0f);
}

// agg2[dst] += x[src] * dinv[src]   (dinv[dst] factored out -> applied in
// lstm phase A; weight matrix commuted past the sum by linearity).
__global__ void scatter_kernel(const int* __restrict__ idx, int E,
                               const float2* __restrict__ x2,
                               const float* __restrict__ dinv,
                               float* __restrict__ agg2) {
    int e = blockIdx.x * blockDim.x + threadIdx.x;
    if (e < E) {
        int s = idx[e];
        int d = idx[E + e];
        float ns = dinv[s];
        float2 xs = x2[s];
        atomicAdd(&agg2[2 * d + 0], xs.x * ns);
        atomicAdd(&agg2[2 * d + 1], xs.y * ns);
    }
}

// ---------------- fused GCN-epilogue + LSTM + FC ----------------
// One wave per node. Lane l owns gate rows l and l+64 (rows 0..31=i, 32..63=f,
// 64..95=g, 96..127=o):  lane<32 -> (i[l], g[l]);  lane>=32 -> (f[l-32], o[l-32]).
// Weights for the two owned rows are REGISTER-resident: 32 float4 = 128 VGPR.
// Rounds 1+3 showed the allocator rematerializes these loads into the loop
// (VGPR_Count=84): the opaque `asm volatile` pin below makes each value the
// output of an un-rematerializable asm so RA must keep it live in a VGPR.
__device__ __forceinline__ void pin4(float4& v) {
    asm volatile("" : "+v"(v.x), "+v"(v.y), "+v"(v.z), "+v"(v.w));
}

__global__ __launch_bounds__(64, 2) void lstm_kernel(
    const float2* __restrict__ x2, const float* __restrict__ dinv,
    const float2* __restrict__ agg2,
    const float* __restrict__ gcn_W, const float* __restrict__ gcn_b,
    const float* __restrict__ w_ih, const float* __restrict__ w_hh,
    const float* __restrict__ b_ih, const float* __restrict__ b_hh,
    const float* __restrict__ fc_W, const float* __restrict__ fc_b,
    float* __restrict__ out) {
    __shared__ float2 uarr[SEQ_LEN];   // pre-GCN-linear 2-vec per timestep
    __shared__ float4 xgbuf[HID / 4];  // xg_t (32 floats)
    __shared__ float4 hbuf[HID / 4];   // h_t  (32 floats)

    const int node = blockIdx.x;
    const int lane = threadIdx.x;
    const int k = lane & 31;
    const bool lo = lane < 32;
    const int rbase = node * SEQ_LEN;

    // Phase A: u[t] = dinv[r] * (agg2[r] + x[r] * dinv[r])   (self-loop folded)
    #pragma unroll
    for (int p = 0; p < 2; ++p) {
        int t = lane + p * 64;
        int r = rbase + t;
        float dv = dinv[r];
        float2 a = agg2[r];
        float2 xx = x2[r];
        uarr[t] = make_float2(dv * fmaf(xx.x, dv, a.x), dv * fmaf(xx.y, dv, a.y));
    }

    // Per-lane weights: rows (lane) and (lane+64) of w_ih / w_hh -> registers.
    float4 wia[8], wib[8], wha[8], whb[8];
    const float4* wi4 = reinterpret_cast<const float4*>(w_ih);
    const float4* wh4 = reinterpret_cast<const float4*>(w_hh);
    #pragma unroll
    for (int kk = 0; kk < 8; ++kk) {
        wia[kk] = wi4[lane * 8 + kk];
        wib[kk] = wi4[(lane + 64) * 8 + kk];
        wha[kk] = wh4[lane * 8 + kk];
        whb[kk] = wh4[(lane + 64) * 8 + kk];
    }
    #pragma unroll
    for (int kk = 0; kk < 8; ++kk) {
        pin4(wia[kk]); pin4(wib[kk]); pin4(wha[kk]); pin4(whb[kk]);
    }
    const float bsa = b_ih[lane] + b_hh[lane];
    const float bsb = b_ih[lane + 64] + b_hh[lane + 64];

    // GCN linear constants (column k of W, bias k) — used by lo half.
    const float W0 = gcn_W[k];
    const float W1 = gcn_W[HID + k];
    const float gb = gcn_b[k];

    // act_b: lo lanes need tanh(g)=2*sigm(2g)-1; hi lanes need sigm(o).
    const float nb_scale = lo ? -2.0f : -1.0f;
    const float mb = lo ? 2.0f : 1.0f;
    const float ab = lo ? -1.0f : 0.0f;

    if (lo) ((float*)hbuf)[k] = 0.0f;
    float c = 0.0f;
    float hn = 0.0f;
    __builtin_amdgcn_wave_barrier();

    for (int t = 0; t < SEQ_LEN; ++t) {
        if (lo) {
            float2 u = uarr[t];
            float xg = fmaf(u.x, W0, fmaf(u.y, W1, gb));
            ((float*)xgbuf)[k] = fmaxf(xg, 0.0f);
        }
        __builtin_amdgcn_wave_barrier();

        float axa = 0.0f, aha = 0.0f, axb = 0.0f, ahb = 0.0f;  // 4 indep chains
        #pragma unroll
        for (int kk = 0; kk < 8; ++kk) {
            float4 xv = xgbuf[kk];
            float4 hv = hbuf[kk];
            axa = fmaf(xv.x, wia[kk].x, axa);
            axa = fmaf(xv.y, wia[kk].y, axa);
            axa = fmaf(xv.z, wia[kk].z, axa);
            axa = fmaf(xv.w, wia[kk].w, axa);
            aha = fmaf(hv.x, wha[kk].x, aha);
            aha = fmaf(hv.y, wha[kk].y, aha);
            aha = fmaf(hv.z, wha[kk].z, aha);
            aha = fmaf(hv.w, wha[kk].w, aha);
            axb = fmaf(xv.x, wib[kk].x, axb);
            axb = fmaf(xv.y, wib[kk].y, axb);
            axb = fmaf(xv.z, wib[kk].z, axb);
            axb = fmaf(xv.w, wib[kk].w, axb);
            ahb = fmaf(hv.x, whb[kk].x, ahb);
            ahb = fmaf(hv.y, whb[kk].y, ahb);
            ahb = fmaf(hv.z, whb[kk].z, ahb);
            ahb = fmaf(hv.w, whb[kk].w, ahb);
        }
        float ga = bsa + axa + aha;   // row lane   : i (lo) / f (hi)
        float gbv = bsb + axb + ahb;  // row lane+64: g (lo) / o (hi)

        float ea = __expf(-ga);
        float act_a = __fdividef(1.0f, 1.0f + ea);                // sigmoid
        float eb = __expf(gbv * nb_scale);
        float act_b = fmaf(__fdividef(1.0f, 1.0f + eb), mb, ab);  // tanh | sigm

        float oth_a = __shfl_xor(act_a, 32);
        float oth_b = __shfl_xor(act_b, 32);
        float ii = lo ? act_a : oth_a;
        float gg = lo ? act_b : oth_b;
        float ff = lo ? oth_a : act_a;
        float oo = lo ? oth_b : act_b;

        c = fmaf(ff, c, ii * gg);
        float ec = __expf(-2.0f * c);
        float th = fmaf(__fdividef(1.0f, 1.0f + ec), 2.0f, -1.0f);  // tanh(c)
        hn = oo * th;

        __builtin_amdgcn_wave_barrier();
        if (lo) ((float*)hbuf)[k] = hn;
        __builtin_amdgcn_wave_barrier();
    }

    // FC epilogue: both halves hold identical hn per unit k; reduce 32 lanes.
    float val = hn * fc_W[k];
    #pragma unroll
    for (int off = 16; off; off >>= 1) val += __shfl_xor(val, off);
    if (lane == 0) out[node] = val + fc_b[0];
}

extern "C" void kernel_launch(void* const* d_in, const int* in_sizes, int n_in,
                              void* d_out, int out_size, void* d_ws, size_t ws_size,
                              hipStream_t stream) {
    const float* x     = (const float*)d_in[0];
    const int*   idx   = (const int*)d_in[1];
    const float* gcn_W = (const float*)d_in[2];
    const float* gcn_b = (const float*)d_in[3];
    const float* w_ih  = (const float*)d_in[4];
    const float* w_hh  = (const float*)d_in[5];
    const float* b_ih  = (const float*)d_in[6];
    const float* b_hh  = (const float*)d_in[7];
    const float* fc_W  = (const float*)d_in[8];
    const float* fc_b  = (const float*)d_in[9];

    const int num_nodes = in_sizes[0] / (SEQ_LEN * IN_FEATS);
    const int ntot = num_nodes * SEQ_LEN;
    const int E = in_sizes[1] / 2;

    // ws layout: [dinv: ntot floats][agg2: ntot float2]
    float* dinv = (float*)d_ws;
    float* agg2 = dinv + ntot;

    hipMemsetAsync(d_ws, 0, (size_t)ntot * sizeof(float) * 3, stream);

    count_kernel<<<(E + 255) / 256, 256, 0, stream>>>(idx, E, (int*)dinv);
    dinv_kernel<<<(ntot + 255) / 256, 256, 0, stream>>>(dinv, ntot);
    scatter_kernel<<<(E + 255) / 256, 256, 0, stream>>>(
        idx, E, (const float2*)x, dinv, agg2);
    lstm_kernel<<<num_nodes, 64, 0, stream>>>(
        (const float2*)x, dinv, (const float2*)agg2,
        gcn_W, gcn_b, w_ih, w_hh, b_ih, b_hh, fc_W, fc_b,
        (float*)d_out);
}

// Round 5
// 879.132 us; speedup vs baseline: 1.7041x; 1.2359x over previous
//
#include <hip/hip_runtime.h>

#define SEQ 128
#define HID 32

typedef __attribute__((ext_vector_type(8))) short short8;   // 8 bf16 = 4 VGPR
typedef __attribute__((ext_vector_type(4))) float floatx4;  // MFMA acc

// ---------------- GCN prep ----------------

__global__ void count_kernel(const int* __restrict__ idx, int E, int* __restrict__ cnt) {
    int e = blockIdx.x * blockDim.x + threadIdx.x;
    if (e < E) atomicAdd(&cnt[idx[E + e]], 1);
}

__global__ void dinv_kernel(float* __restrict__ buf, int n) {
    int i = blockIdx.x * blockDim.x + threadIdx.x;
    if (i < n) buf[i] = rsqrtf((float)__float_as_int(buf[i]) + 1.0f);
}

// agg2[dst] += x[src] * dinv[src]   (dinv[dst] applied in lstm phase; W commuted)
__global__ void scatter_kernel(const int* __restrict__ idx, int E,
                               const float2* __restrict__ x2,
                               const float* __restrict__ dinv,
                               float* __restrict__ agg2) {
    int e = blockIdx.x * blockDim.x + threadIdx.x;
    if (e < E) {
        int s = idx[e];
        int d = idx[E + e];
        float ns = dinv[s];
        float2 xs = x2[s];
        atomicAdd(&agg2[2 * d + 0], xs.x * ns);
        atomicAdd(&agg2[2 * d + 1], xs.y * ns);
    }
}

// ---------------- MFMA LSTM ----------------
// One wave = 16 nodes. Per step: G^T[128 gates x 16 nodes] = W*[xg;h]^T via
// 8 M-tiles of mfma_f32_16x16x32_bf16 (A = weights, constant in VGPRs;
// B = per-step activations). Row permutation u(mtl,m)=8(m>>2)+4*mtl+(m&3)
// makes the C/D output slot (tile,quad,reg) == unit 8q+(4*mtl+reg), which is
// exactly the next step's B-frag element k=8q+j -> zero-shuffle recurrence.
// hi/lo bf16 split (3-term) of weights AND activations ~= fp32 precision.

__device__ __forceinline__ float sigm_f(float x) {
    return __fdividef(1.0f, 1.0f + __expf(-x));
}
__device__ __forceinline__ float tanh_f(float x) {
    return 1.0f - __fdividef(2.0f, __expf(2.0f * x) + 1.0f);
}
// truncation split: f = hi + lo exactly up to lo's truncation (~2^-16 rel)
__device__ __forceinline__ void bsplit(float f, short& hi, short& lo) {
    unsigned u = __float_as_uint(f);
    hi = (short)(u >> 16);
    float r = f - __uint_as_float(u & 0xFFFF0000u);
    lo = (short)(__float_as_uint(r) >> 16);
}

__global__ __launch_bounds__(64, 1) void lstm_mfma_kernel(
    const float2* __restrict__ x2, const float* __restrict__ dinv,
    const float2* __restrict__ agg2, int N,
    const float* __restrict__ gcn_W, const float* __restrict__ gcn_b,
    const float* __restrict__ w_ih, const float* __restrict__ w_hh,
    const float* __restrict__ b_ih, const float* __restrict__ b_hh,
    const float* __restrict__ fc_W, const float* __restrict__ fc_b,
    float* __restrict__ out) {
    const int lane = threadIdx.x;
    const int l15 = lane & 15;
    const int q = lane >> 4;
    int node = blockIdx.x * 16 + l15;
    const bool valid = node < N;
    if (!valid) node = N - 1;

    // ---- constant A-frags: W rows permuted into tiles, hi/lo bf16 ----
    // Tile T = gate*2 + mtl (gate 0..3 = i,f,g,o). A[m=l15][k=8q+j].
    short8 AiH[8], AiL[8], AhH[8], AhL[8];
    floatx4 biasC[8];
    #pragma unroll
    for (int T = 0; T < 8; ++T) {
        const int gate = T >> 1, mtl = T & 1;
        const int arow = gate * 32 + 8 * (l15 >> 2) + 4 * mtl + (l15 & 3);
        const float* wi = w_ih + arow * HID + 8 * q;
        const float* wh = w_hh + arow * HID + 8 * q;
        #pragma unroll
        for (int j = 0; j < 8; ++j) {
            short h16, l16;
            bsplit(wi[j], h16, l16); AiH[T][j] = h16; AiL[T][j] = l16;
            bsplit(wh[j], h16, l16); AhH[T][j] = h16; AhL[T][j] = l16;
        }
        #pragma unroll
        for (int r = 0; r < 4; ++r) {
            const int brow = gate * 32 + 8 * q + 4 * mtl + r;
            biasC[T][r] = b_ih[brow] + b_hh[brow];
        }
    }

    // ---- per-lane GCN / FC constants for units u = 8q+j ----
    float wg0[8], wg1[8], gbc[8], fcw[8];
    #pragma unroll
    for (int j = 0; j < 8; ++j) {
        const int u = 8 * q + j;
        wg0[j] = gcn_W[u];
        wg1[j] = gcn_W[HID + u];
        gbc[j] = gcn_b[u];
        fcw[j] = fc_W[u];
    }

    // ---- state ----
    short8 hh, hl;
    float c[8], ho[8];
    #pragma unroll
    for (int j = 0; j < 8; ++j) { hh[j] = 0; hl[j] = 0; c[j] = 0.0f; ho[j] = 0.0f; }

    const float2* agp = agg2 + (size_t)node * SEQ;
    const float2* xp  = x2   + (size_t)node * SEQ;
    const float*  dp  = dinv + (size_t)node * SEQ;

    float2 ag = agp[0];
    float2 xv = xp[0];
    float  dv = dp[0];

    #pragma unroll 1
    for (int t = 0; t < SEQ; ++t) {
        const int tn = (t + 1 < SEQ) ? t + 1 : SEQ - 1;
        float2 agn = agp[tn];
        float2 xvn = xp[tn];
        float  dvn = dp[tn];

        // GCN pre-linear 2-vec with self-loop folded: u = dv*(agg + x*dv)
        const float ux = dv * fmaf(xv.x, dv, ag.x);
        const float uy = dv * fmaf(xv.y, dv, ag.y);

        // xg for units 8q+j (B-frag layout), hi/lo split
        short8 xh, xl;
        #pragma unroll
        for (int j = 0; j < 8; ++j) {
            float g = fmaxf(fmaf(ux, wg0[j], fmaf(uy, wg1[j], gbc[j])), 0.0f);
            short h16, l16;
            bsplit(g, h16, l16);
            xh[j] = h16; xl[j] = l16;
        }

        // 8 M-tiles x (3 xg-terms + 3 h-terms), bias as C init
        floatx4 acc[8];
        #pragma unroll
        for (int T = 0; T < 8; ++T) {
            floatx4 a = biasC[T];
            a = __builtin_amdgcn_mfma_f32_16x16x32_bf16(AiH[T], xh, a, 0, 0, 0);
            a = __builtin_amdgcn_mfma_f32_16x16x32_bf16(AiH[T], xl, a, 0, 0, 0);
            a = __builtin_amdgcn_mfma_f32_16x16x32_bf16(AiL[T], xh, a, 0, 0, 0);
            a = __builtin_amdgcn_mfma_f32_16x16x32_bf16(AhH[T], hh, a, 0, 0, 0);
            a = __builtin_amdgcn_mfma_f32_16x16x32_bf16(AhH[T], hl, a, 0, 0, 0);
            a = __builtin_amdgcn_mfma_f32_16x16x32_bf16(AhL[T], hh, a, 0, 0, 0);
            acc[T] = a;
        }

        // activations + cell update, elementwise in C-layout.
        // slot j (= 4*mtl + r): unit 8q+j of node l15; gate g lives in acc[2g + (j>>2)][j&3]
        #pragma unroll
        for (int j = 0; j < 8; ++j) {
            const int tt = j >> 2, r = j & 3;
            const float ig = sigm_f(acc[0 + tt][r]);
            const float fg = sigm_f(acc[2 + tt][r]);
            const float gg = tanh_f(acc[4 + tt][r]);
            const float og = sigm_f(acc[6 + tt][r]);
            c[j] = fmaf(fg, c[j], ig * gg);
            const float hv = og * tanh_f(c[j]);
            ho[j] = hv;
            short h16, l16;
            bsplit(hv, h16, l16);
            hh[j] = h16; hl[j] = l16;
        }

        ag = agn; xv = xvn; dv = dvn;
    }

    // ---- FC epilogue: out[node] = sum_u h[u]*fcW[u] + fcb ----
    float partial = 0.0f;
    #pragma unroll
    for (int j = 0; j < 8; ++j) partial = fmaf(ho[j], fcw[j], partial);
    partial += __shfl_xor(partial, 16);
    partial += __shfl_xor(partial, 32);
    if (q == 0 && valid) out[node] = partial + fc_b[0];
}

extern "C" void kernel_launch(void* const* d_in, const int* in_sizes, int n_in,
                              void* d_out, int out_size, void* d_ws, size_t ws_size,
                              hipStream_t stream) {
    const float* x     = (const float*)d_in[0];
    const int*   idx   = (const int*)d_in[1];
    const float* gcn_W = (const float*)d_in[2];
    const float* gcn_b = (const float*)d_in[3];
    const float* w_ih  = (const float*)d_in[4];
    const float* w_hh  = (const float*)d_in[5];
    const float* b_ih  = (const float*)d_in[6];
    const float* b_hh  = (const float*)d_in[7];
    const float* fc_W  = (const float*)d_in[8];
    const float* fc_b  = (const float*)d_in[9];

    const int num_nodes = in_sizes[0] / (SEQ * 2);
    const int ntot = num_nodes * SEQ;
    const int E = in_sizes[1] / 2;

    // ws layout: [dinv: ntot floats][agg2: ntot float2]
    float* dinv = (float*)d_ws;
    float* agg2 = dinv + ntot;

    hipMemsetAsync(d_ws, 0, (size_t)ntot * sizeof(float) * 3, stream);

    count_kernel<<<(E + 255) / 256, 256, 0, stream>>>(idx, E, (int*)dinv);
    dinv_kernel<<<(ntot + 255) / 256, 256, 0, stream>>>(dinv, ntot);
    scatter_kernel<<<(E + 255) / 256, 256, 0, stream>>>(
        idx, E, (const float2*)x, dinv, agg2);
    lstm_mfma_kernel<<<(num_nodes + 15) / 16, 64, 0, stream>>>(
        (const float2*)x, dinv, (const float2*)agg2, num_nodes,
        gcn_W, gcn_b, w_ih, w_hh, b_ih, b_hh, fc_W, fc_b,
        (float*)d_out);
}

// Round 6
// 707.533 us; speedup vs baseline: 2.1174x; 1.2425x over previous
//
#include <hip/hip_runtime.h>

#define SEQ 128
#define HID 32
#define TPB 128   // 2 waves, 16 nodes per block

typedef __attribute__((ext_vector_type(8))) short short8;   // 8 bf16 = 4 VGPR
typedef __attribute__((ext_vector_type(4))) float floatx4;  // MFMA acc

// ---------------- GCN prep ----------------

__global__ void count_kernel(const int* __restrict__ idx, int E, int* __restrict__ cnt) {
    int e = blockIdx.x * blockDim.x + threadIdx.x;
    if (e < E) atomicAdd(&cnt[idx[E + e]], 1);
}

__global__ void dinv_kernel(float* __restrict__ buf, int n) {
    int i = blockIdx.x * blockDim.x + threadIdx.x;
    if (i < n) buf[i] = rsqrtf((float)__float_as_int(buf[i]) + 1.0f);
}

// agg2[dst] += x[src] * dinv[src]  (dinv[dst] applied in lstm staging; W commuted)
__global__ void scatter_kernel(const int* __restrict__ idx, int E,
                               const float2* __restrict__ x2,
                               const float* __restrict__ dinv,
                               float* __restrict__ agg2) {
    int e = blockIdx.x * blockDim.x + threadIdx.x;
    if (e < E) {
        int s = idx[e];
        int d = idx[E + e];
        float ns = dinv[s];
        float2 xs = x2[s];
        atomicAdd(&agg2[2 * d + 0], xs.x * ns);
        atomicAdd(&agg2[2 * d + 1], xs.y * ns);
    }
}

// ---------------- MFMA LSTM, 2 waves / 16 nodes ----------------
// Wave w owns the mtl=w half of the row-permuted W tiles (4 tiles = gates
// i,f,g,o for units 8q+4w+r). C/D slot (q,r) == unit 8q+4w+r == B-frag element
// k=8q+(4w+r) -> zero-shuffle recurrence (HW-verified in round 5). The h halves
// cross the wave boundary through a double-buffered packed-uint LDS buffer
// (read buf[p], write buf[p^1], one __syncthreads per step).

__device__ __forceinline__ float sigm_f(float x) {
    return __fdividef(1.0f, 1.0f + __expf(-x));
}
__device__ __forceinline__ float tanh_f(float x) {
    return 1.0f - __fdividef(2.0f, __expf(2.0f * x) + 1.0f);
}
// hi/lo truncation split packed as (hi16<<16)|lo16
__device__ __forceinline__ unsigned packsplit(float f) {
    unsigned u = __float_as_uint(f);
    float r = f - __uint_as_float(u & 0xFFFF0000u);
    return (u & 0xFFFF0000u) | (__float_as_uint(r) >> 16);
}

__global__ __launch_bounds__(TPB, 2) void lstm_mfma2_kernel(
    const float2* __restrict__ x2, const float* __restrict__ dinv,
    const float2* __restrict__ agg2, int N,
    const float* __restrict__ gcn_W, const float* __restrict__ gcn_b,
    const float* __restrict__ w_ih, const float* __restrict__ w_hh,
    const float* __restrict__ b_ih, const float* __restrict__ b_hh,
    const float* __restrict__ fc_W, const float* __restrict__ fc_b,
    float* __restrict__ out) {
    __shared__ float2 ubuf[16][SEQ + 1];   // u (GCN pre-linear), +1 pad: bank-free broadcast
    __shared__ unsigned hx[2][16][33];     // packed h hi|lo, stride 33: <=2-way banks
    __shared__ float fcp[2][16];

    const int tid = threadIdx.x;
    const int w = tid >> 6;       // wave id = mtl
    const int lane = tid & 63;
    const int l15 = lane & 15;
    const int q = lane >> 4;
    const int base = blockIdx.x * 16;

    // ---- Phase A: stage u[node][t] = dv*(agg + x*dv) into LDS (coalesced) ----
    {
        const float2* agb = agg2 + (size_t)base * SEQ;
        const float2* xb  = x2   + (size_t)base * SEQ;
        const float*  db  = dinv + (size_t)base * SEQ;
        const int lim = min(16 * SEQ, (N - base) * SEQ);
        for (int i = tid; i < 16 * SEQ; i += TPB) {
            float2 v = make_float2(0.f, 0.f);
            if (i < lim) {
                float dv = db[i];
                float2 a = agb[i];
                float2 xx = xb[i];
                v = make_float2(dv * fmaf(xx.x, dv, a.x), dv * fmaf(xx.y, dv, a.y));
            }
            ubuf[i >> 7][i & 127] = v;
        }
        unsigned* h0 = &hx[0][0][0];
        for (int i = tid; i < 16 * 33; i += TPB) h0[i] = 0;  // h(0) = 0
    }

    // ---- constant A-frags (4 tiles = 4 gates at mtl=w), hi/lo bf16 ----
    short8 AiH[4], AiL[4], AhH[4], AhL[4];
    floatx4 biasC[4];
    #pragma unroll
    for (int g = 0; g < 4; ++g) {
        const int arow = g * 32 + 8 * (l15 >> 2) + 4 * w + (l15 & 3);
        const float* wi = w_ih + arow * HID + 8 * q;
        const float* wh = w_hh + arow * HID + 8 * q;
        #pragma unroll
        for (int j = 0; j < 8; ++j) {
            unsigned pi = packsplit(wi[j]);
            AiH[g][j] = (short)(pi >> 16); AiL[g][j] = (short)(pi & 0xFFFF);
            unsigned ph = packsplit(wh[j]);
            AhH[g][j] = (short)(ph >> 16); AhL[g][j] = (short)(ph & 0xFFFF);
        }
        #pragma unroll
        for (int r = 0; r < 4; ++r) {
            const int brow = g * 32 + 8 * q + 4 * w + r;
            biasC[g][r] = b_ih[brow] + b_hh[brow];
        }
    }

    // ---- GCN consts for B-frag units 8q+j; FC consts for own units ----
    float wg0[8], wg1[8], gbc[8], fcw[4];
    #pragma unroll
    for (int j = 0; j < 8; ++j) {
        const int u = 8 * q + j;
        wg0[j] = gcn_W[u];
        wg1[j] = gcn_W[HID + u];
        gbc[j] = gcn_b[u];
    }
    #pragma unroll
    for (int r = 0; r < 4; ++r) fcw[r] = fc_W[8 * q + 4 * w + r];

    float c[4] = {0.f, 0.f, 0.f, 0.f};
    float ho[4] = {0.f, 0.f, 0.f, 0.f};

    __syncthreads();  // staging + h0 visible

    int p = 0;
    #pragma unroll 1
    for (int t = 0; t < SEQ; ++t) {
        // xg for all B-frag units (both waves duplicate; pure fn of LDS u)
        float2 uu = ubuf[l15][t];
        short8 xh, xl;
        #pragma unroll
        for (int j = 0; j < 8; ++j) {
            float g = fmaxf(fmaf(uu.x, wg0[j], fmaf(uu.y, wg1[j], gbc[j])), 0.f);
            unsigned pk = packsplit(g);
            xh[j] = (short)(pk >> 16); xl[j] = (short)(pk & 0xFFFF);
        }

        // h(t-1) full frag from LDS (own half included; broadcast-friendly)
        short8 hh, hl;
        #pragma unroll
        for (int j = 0; j < 8; ++j) {
            unsigned pv = hx[p][l15][8 * q + j];
            hh[j] = (short)(pv >> 16); hl[j] = (short)(pv & 0xFFFF);
        }

        // term-major MFMA: 4 independent chains, dep distance 4
        floatx4 acc[4];
        #pragma unroll
        for (int g = 0; g < 4; ++g) acc[g] = biasC[g];
        #pragma unroll
        for (int g = 0; g < 4; ++g) acc[g] = __builtin_amdgcn_mfma_f32_16x16x32_bf16(AiH[g], xh, acc[g], 0, 0, 0);
        #pragma unroll
        for (int g = 0; g < 4; ++g) acc[g] = __builtin_amdgcn_mfma_f32_16x16x32_bf16(AiL[g], xh, acc[g], 0, 0, 0);
        #pragma unroll
        for (int g = 0; g < 4; ++g) acc[g] = __builtin_amdgcn_mfma_f32_16x16x32_bf16(AiH[g], xl, acc[g], 0, 0, 0);
        #pragma unroll
        for (int g = 0; g < 4; ++g) acc[g] = __builtin_amdgcn_mfma_f32_16x16x32_bf16(AhH[g], hh, acc[g], 0, 0, 0);
        #pragma unroll
        for (int g = 0; g < 4; ++g) acc[g] = __builtin_amdgcn_mfma_f32_16x16x32_bf16(AhL[g], hh, acc[g], 0, 0, 0);
        #pragma unroll
        for (int g = 0; g < 4; ++g) acc[g] = __builtin_amdgcn_mfma_f32_16x16x32_bf16(AhH[g], hl, acc[g], 0, 0, 0);

        // activations + cell update for own units 8q+4w+r
        #pragma unroll
        for (int r = 0; r < 4; ++r) {
            const float ig = sigm_f(acc[0][r]);
            const float fg = sigm_f(acc[1][r]);
            const float gg = tanh_f(acc[2][r]);
            const float og = sigm_f(acc[3][r]);
            c[r] = fmaf(fg, c[r], ig * gg);
            const float hv = og * tanh_f(c[r]);
            ho[r] = hv;
            hx[p ^ 1][l15][8 * q + 4 * w + r] = packsplit(hv);
        }

        __syncthreads();
        p ^= 1;
    }

    // ---- FC epilogue ----
    float partial = fmaf(ho[0], fcw[0], fmaf(ho[1], fcw[1],
                    fmaf(ho[2], fcw[2], ho[3] * fcw[3])));
    partial += __shfl_xor(partial, 16);
    partial += __shfl_xor(partial, 32);
    if (lane < 16) fcp[w][l15] = partial;
    __syncthreads();
    if (w == 0 && lane < 16) {
        const int node = base + l15;
        if (node < N) out[node] = fcp[0][l15] + fcp[1][l15] + fc_b[0];
    }
}

extern "C" void kernel_launch(void* const* d_in, const int* in_sizes, int n_in,
                              void* d_out, int out_size, void* d_ws, size_t ws_size,
                              hipStream_t stream) {
    const float* x     = (const float*)d_in[0];
    const int*   idx   = (const int*)d_in[1];
    const float* gcn_W = (const float*)d_in[2];
    const float* gcn_b = (const float*)d_in[3];
    const float* w_ih  = (const float*)d_in[4];
    const float* w_hh  = (const float*)d_in[5];
    const float* b_ih  = (const float*)d_in[6];
    const float* b_hh  = (const float*)d_in[7];
    const float* fc_W  = (const float*)d_in[8];
    const float* fc_b  = (const float*)d_in[9];

    const int num_nodes = in_sizes[0] / (SEQ * 2);
    const int ntot = num_nodes * SEQ;
    const int E = in_sizes[1] / 2;

    float* dinv = (float*)d_ws;
    float* agg2 = dinv + ntot;

    hipMemsetAsync(d_ws, 0, (size_t)ntot * sizeof(float) * 3, stream);

    count_kernel<<<(E + 255) / 256, 256, 0, stream>>>(idx, E, (int*)dinv);
    dinv_kernel<<<(ntot + 255) / 256, 256, 0, stream>>>(dinv, ntot);
    scatter_kernel<<<(E + 255) / 256, 256, 0, stream>>>(
        idx, E, (const float2*)x, dinv, agg2);
    lstm_mfma2_kernel<<<(num_nodes + 15) / 16, TPB, 0, stream>>>(
        (const float2*)x, dinv, (const float2*)agg2, num_nodes,
        gcn_W, gcn_b, w_ih, w_hh, b_ih, b_hh, fc_W, fc_b,
        (float*)d_out);
}

// Round 7
// 579.948 us; speedup vs baseline: 2.5833x; 1.2200x over previous
//
#include <hip/hip_runtime.h>

#define SEQ 128
#define HID 32
#define TPB 128   // 2 waves, 16 nodes per block

typedef __attribute__((ext_vector_type(8))) short short8;   // 8 bf16 = 4 VGPR
typedef __attribute__((ext_vector_type(4))) short short4v;  // 4 shorts = 8B
typedef __attribute__((ext_vector_type(4))) float floatx4;  // MFMA acc

// ---------------- GCN prep ----------------

__global__ void count_kernel(const int* __restrict__ idx, int E, int* __restrict__ cnt) {
    int e = blockIdx.x * blockDim.x + threadIdx.x;
    if (e < E) atomicAdd(&cnt[idx[E + e]], 1);
}

__global__ void dinv_kernel(float* __restrict__ buf, int n) {
    int i = blockIdx.x * blockDim.x + threadIdx.x;
    if (i < n) buf[i] = rsqrtf((float)__float_as_int(buf[i]) + 1.0f);
}

// agg2[dst] += x[src] * dinv[src]  (dinv[dst] applied in lstm staging; W commuted)
__global__ void scatter_kernel(const int* __restrict__ idx, int E,
                               const float2* __restrict__ x2,
                               const float* __restrict__ dinv,
                               float* __restrict__ agg2) {
    int e = blockIdx.x * blockDim.x + threadIdx.x;
    if (e < E) {
        int s = idx[e];
        int d = idx[E + e];
        float ns = dinv[s];
        float2 xs = x2[s];
        atomicAdd(&agg2[2 * d + 0], xs.x * ns);
        atomicAdd(&agg2[2 * d + 1], xs.y * ns);
    }
}

// ---------------- MFMA LSTM, 2 waves / 16 nodes, low-glue ----------------
// Wave w owns gates i,f,g,o for units 8q+4w+r (row-permuted W tiles; layout
// HW-verified rounds 5/6). h and xg cross the wave boundary through LDS rows
// of SEPARATED hi/lo shorts (32 units x 2B, stride 96B): one ds_read_b128 at
// [l15*96 + 16q] IS the lane's short8 B-frag -> zero unpack VALU.
// Single barrier per step: epoch reads buf p (xg(t), h(t-1)), writes buf p^1
// (xg(t+1), h(t)) -- double-buffer makes one __syncthreads race-free.

__device__ __forceinline__ float sigm_f(float x) {
    return __builtin_amdgcn_rcpf(1.0f + __expf(-x));
}
__device__ __forceinline__ float tanh_f(float x) {
    return fmaf(__builtin_amdgcn_rcpf(1.0f + __expf(-2.0f * x)), 2.0f, -1.0f);
}
// truncation split: f = hi + lo (~2^-16 rel); 3-term MFMA keeps fp32-like precision
__device__ __forceinline__ void fsplit(float f, short& hi, short& lo) {
    unsigned u = __float_as_uint(f);
    hi = (short)(u >> 16);
    float r = f - __uint_as_float(u & 0xFFFF0000u);
    lo = (short)(__float_as_uint(r) >> 16);
}

__global__ __launch_bounds__(TPB, 2) void lstm_mfma3_kernel(
    const float2* __restrict__ x2, const float* __restrict__ dinv,
    const float2* __restrict__ agg2, int N,
    const float* __restrict__ gcn_W, const float* __restrict__ gcn_b,
    const float* __restrict__ w_ih, const float* __restrict__ w_hh,
    const float* __restrict__ b_ih, const float* __restrict__ b_hh,
    const float* __restrict__ fc_W, const float* __restrict__ fc_b,
    float* __restrict__ out) {
    __shared__ float2 ubuf[16][SEQ + 1];                 // 16.5 KB (col 128 = scratch)
    __shared__ __align__(16) short xgh[2][16][48];       // xg hi, row=32 units + pad
    __shared__ __align__(16) short xgl[2][16][48];       // xg lo
    __shared__ __align__(16) short hhb[2][16][48];       // h hi
    __shared__ __align__(16) short hlb[2][16][48];       // h lo
    __shared__ float fcp[2][16];

    const int tid = threadIdx.x;
    const int w = tid >> 6;       // wave id = mtl
    const int lane = tid & 63;
    const int l15 = lane & 15;
    const int q = lane >> 4;
    const int base = blockIdx.x * 16;

    // ---- Phase A: stage u[node][t] = dv*(agg + x*dv) into LDS (coalesced) ----
    {
        const float2* agb = agg2 + (size_t)base * SEQ;
        const float2* xb  = x2   + (size_t)base * SEQ;
        const float*  db  = dinv + (size_t)base * SEQ;
        const int lim = min(16 * SEQ, (N - base) * SEQ);
        for (int i = tid; i < 16 * SEQ; i += TPB) {
            float2 v = make_float2(0.f, 0.f);
            if (i < lim) {
                float dv = db[i];
                float2 a = agb[i];
                float2 xx = xb[i];
                v = make_float2(dv * fmaf(xx.x, dv, a.x), dv * fmaf(xx.y, dv, a.y));
            }
            ubuf[i >> 7][i & 127] = v;
        }
    }

    // ---- constant A-frags (4 tiles = gates i,f,g,o at mtl=w), hi/lo bf16 ----
    short8 AiH[4], AiL[4], AhH[4], AhL[4];
    floatx4 biasC[4];
    #pragma unroll
    for (int g = 0; g < 4; ++g) {
        const int arow = g * 32 + 8 * (l15 >> 2) + 4 * w + (l15 & 3);
        const float* wi = w_ih + arow * HID + 8 * q;
        const float* wh = w_hh + arow * HID + 8 * q;
        #pragma unroll
        for (int j = 0; j < 8; ++j) {
            short h16, l16;
            fsplit(wi[j], h16, l16); AiH[g][j] = h16; AiL[g][j] = l16;
            fsplit(wh[j], h16, l16); AhH[g][j] = h16; AhL[g][j] = l16;
        }
        #pragma unroll
        for (int r = 0; r < 4; ++r) {
            const int brow = g * 32 + 8 * q + 4 * w + r;
            biasC[g][r] = b_ih[brow] + b_hh[brow];
        }
    }

    // ---- GCN consts for xg units owned by THIS lane: u = 16w + 4q + r ----
    float wg0[4], wg1[4], gbc[4], fcw[4];
    #pragma unroll
    for (int r = 0; r < 4; ++r) {
        const int u = 16 * w + 4 * q + r;
        wg0[r] = gcn_W[u];
        wg1[r] = gcn_W[HID + u];
        gbc[r] = gcn_b[u];
        fcw[r] = fc_W[8 * q + 4 * w + r];   // FC consts for own C-slots
    }

    float c[4] = {0.f, 0.f, 0.f, 0.f};
    float ho[4] = {0.f, 0.f, 0.f, 0.f};

    __syncthreads();  // ubuf staged

    // ---- prologue: xg(0) and h(-1)=0 into buffer 0 ----
    {
        float2 uu = ubuf[l15][0];
        short hi[4], lo[4];
        #pragma unroll
        for (int r = 0; r < 4; ++r) {
            float g = fmaxf(fmaf(uu.x, wg0[r], fmaf(uu.y, wg1[r], gbc[r])), 0.f);
            fsplit(g, hi[r], lo[r]);
        }
        *(short4v*)&xgh[0][l15][16 * w + 4 * q] = (short4v){hi[0], hi[1], hi[2], hi[3]};
        *(short4v*)&xgl[0][l15][16 * w + 4 * q] = (short4v){lo[0], lo[1], lo[2], lo[3]};
        *(short4v*)&hhb[0][l15][8 * q + 4 * w] = (short4v){0, 0, 0, 0};
        *(short4v*)&hlb[0][l15][8 * q + 4 * w] = (short4v){0, 0, 0, 0};
    }
    __syncthreads();

    int p = 0;
    #pragma unroll 1
    for (int t = 0; t < SEQ; ++t) {
        // B-frags direct from LDS: element j == unit 8q+j  (zero unpack)
        const short8 xh = *(const short8*)&xgh[p][l15][8 * q];
        const short8 xl = *(const short8*)&xgl[p][l15][8 * q];
        const short8 hh = *(const short8*)&hhb[p][l15][8 * q];
        const short8 hl = *(const short8*)&hlb[p][l15][8 * q];

        // term-major MFMA: 4 independent chains (gates), depth 6
        floatx4 acc[4];
        #pragma unroll
        for (int g = 0; g < 4; ++g) acc[g] = biasC[g];
        #pragma unroll
        for (int g = 0; g < 4; ++g) acc[g] = __builtin_amdgcn_mfma_f32_16x16x32_bf16(AiH[g], xh, acc[g], 0, 0, 0);
        #pragma unroll
        for (int g = 0; g < 4; ++g) acc[g] = __builtin_amdgcn_mfma_f32_16x16x32_bf16(AiL[g], xh, acc[g], 0, 0, 0);
        #pragma unroll
        for (int g = 0; g < 4; ++g) acc[g] = __builtin_amdgcn_mfma_f32_16x16x32_bf16(AiH[g], xl, acc[g], 0, 0, 0);
        #pragma unroll
        for (int g = 0; g < 4; ++g) acc[g] = __builtin_amdgcn_mfma_f32_16x16x32_bf16(AhH[g], hh, acc[g], 0, 0, 0);
        #pragma unroll
        for (int g = 0; g < 4; ++g) acc[g] = __builtin_amdgcn_mfma_f32_16x16x32_bf16(AhL[g], hh, acc[g], 0, 0, 0);
        #pragma unroll
        for (int g = 0; g < 4; ++g) acc[g] = __builtin_amdgcn_mfma_f32_16x16x32_bf16(AhH[g], hl, acc[g], 0, 0, 0);

        // xg(t+1) — h-independent; wave w computes its 4 owned units only
        {
            float2 uu = ubuf[l15][t + 1];   // t=127 reads pad col; value never consumed
            short hi[4], lo[4];
            #pragma unroll
            for (int r = 0; r < 4; ++r) {
                float g = fmaxf(fmaf(uu.x, wg0[r], fmaf(uu.y, wg1[r], gbc[r])), 0.f);
                fsplit(g, hi[r], lo[r]);
            }
            *(short4v*)&xgh[p ^ 1][l15][16 * w + 4 * q] = (short4v){hi[0], hi[1], hi[2], hi[3]};
            *(short4v*)&xgl[p ^ 1][l15][16 * w + 4 * q] = (short4v){lo[0], lo[1], lo[2], lo[3]};
        }

        // activations + cell update for own units 8q+4w+r
        {
            short hi[4], lo[4];
            #pragma unroll
            for (int r = 0; r < 4; ++r) {
                const float ig = sigm_f(acc[0][r]);
                const float fg = sigm_f(acc[1][r]);
                const float gg = tanh_f(acc[2][r]);
                const float og = sigm_f(acc[3][r]);
                c[r] = fmaf(fg, c[r], ig * gg);
                const float hv = og * tanh_f(c[r]);
                ho[r] = hv;
                fsplit(hv, hi[r], lo[r]);
            }
            *(short4v*)&hhb[p ^ 1][l15][8 * q + 4 * w] = (short4v){hi[0], hi[1], hi[2], hi[3]};
            *(short4v*)&hlb[p ^ 1][l15][8 * q + 4 * w] = (short4v){lo[0], lo[1], lo[2], lo[3]};
        }

        __syncthreads();
        p ^= 1;
    }

    // ---- FC epilogue ----
    float partial = fmaf(ho[0], fcw[0], fmaf(ho[1], fcw[1],
                    fmaf(ho[2], fcw[2], ho[3] * fcw[3])));
    partial += __shfl_xor(partial, 16);
    partial += __shfl_xor(partial, 32);
    if (lane < 16) fcp[w][l15] = partial;
    __syncthreads();
    if (w == 0 && lane < 16) {
        const int node = base + l15;
        if (node < N) out[node] = fcp[0][l15] + fcp[1][l15] + fc_b[0];
    }
}

extern "C" void kernel_launch(void* const* d_in, const int* in_sizes, int n_in,
                              void* d_out, int out_size, void* d_ws, size_t ws_size,
                              hipStream_t stream) {
    const float* x     = (const float*)d_in[0];
    const int*   idx   = (const int*)d_in[1];
    const float* gcn_W = (const float*)d_in[2];
    const float* gcn_b = (const float*)d_in[3];
    const float* w_ih  = (const float*)d_in[4];
    const float* w_hh  = (const float*)d_in[5];
    const float* b_ih  = (const float*)d_in[6];
    const float* b_hh  = (const float*)d_in[7];
    const float* fc_W  = (const float*)d_in[8];
    const float* fc_b  = (const float*)d_in[9];

    const int num_nodes = in_sizes[0] / (SEQ * 2);
    const int ntot = num_nodes * SEQ;
    const int E = in_sizes[1] / 2;

    float* dinv = (float*)d_ws;
    float* agg2 = dinv + ntot;

    hipMemsetAsync(d_ws, 0, (size_t)ntot * sizeof(float) * 3, stream);

    count_kernel<<<(E + 255) / 256, 256, 0, stream>>>(idx, E, (int*)dinv);
    dinv_kernel<<<(ntot + 255) / 256, 256, 0, stream>>>(dinv, ntot);
    scatter_kernel<<<(E + 255) / 256, 256, 0, stream>>>(
        idx, E, (const float2*)x, dinv, agg2);
    lstm_mfma3_kernel<<<(num_nodes + 15) / 16, TPB, 0, stream>>>(
        (const float2*)x, dinv, (const float2*)agg2, num_nodes,
        gcn_W, gcn_b, w_ih, w_hh, b_ih, b_hh, fc_W, fc_b,
        (float*)d_out);
}